// Round 15
// baseline (79.294 us; speedup 1.0000x reference)
//
#include <hip/hip_runtime.h>

// BEVTrans: out[b, c*5+h, d, w] = bilinear_sample(X[b,c], ix(b,w,h,d), iy(b,w,h,d))
//   (calib row 2 is exactly [0,0,1] in the reference -> z = dz)
// X: [4,256,96,320] f32, calib: [4,3,3] f32, out: [4,1280,100,100] f32
//
// R14 = R13 with ONE flip: plain (through-cache) stores instead of
// nontemporal. Theory: nt bypasses L2/L3 write-combining -> fine-grained HBM
// transactions (~3.1 TB/s effective write); the harness fill kernel (plain
// stores) sustains 6.6-7.0 TB/s. Writes are write-once and line-aligned
// (R12's (h,d,w) plane order), so through-cache loses nothing to RFO.
// Everything else identical to R13 (66.1us): CG=8, 2w/thread, inline coords,
// paired-corner dwordx2 gathers, dwordx2 stores.

#define W_IN  320
#define H_IN  96
#define SLICE (H_IN * W_IN)     // 30720 floats per (b,c)
#define CG    8                 // channels per thread
#define NP2   25000             // 50000 positions / 2 per thread

typedef float f32x2 __attribute__((ext_vector_type(2)));
typedef float f32x2u __attribute__((ext_vector_type(2), aligned(4)));

__global__ __launch_bounds__(256) void bev_kernel(const float* __restrict__ X,
                                                  const float* __restrict__ calib,
                                                  float* __restrict__ out) {
    const int bcg = blockIdx.y;            // b*32 + channel_group
    const int b   = bcg >> 5;
    const int c0  = (bcg & 31) * CG;
    const int t   = blockIdx.x * 256 + threadIdx.x;   // pair index
    if (t >= NP2) return;

    const int item = t * 2;                // (h,d,w) order: out offset == item
    const int h    = item / 10000;
    const int rem  = item - h * 10000;
    const int d    = rem / 100;
    const int w0   = rem - d * 100;        // even; pair never straddles a row

    const float* cb = calib + b * 9;
    const float c00 = cb[0], c01 = cb[1], c02 = cb[2];
    const float c10 = cb[3], c11 = cb[4], c12 = cb[5];

    const float hyv = -3.0f + (float)h;
    const float dzv = 0.1f + 0.2f * (float)d;
    const float inv = 1.0f / dzv;

    int   off[2];
    float W00[2], W01[2], W10[2], W11[2];
    float wsum = 0.0f;
    #pragma unroll
    for (int j = 0; j < 2; ++j) {
        const float wxv = -9.9f + 0.2f * (float)(w0 + j);
        const float ix = 319.0f * inv * (c00 * wxv + c01 * hyv + c02 * dzv);
        const float iy =  95.0f * inv * (c10 * wxv + c11 * hyv + c12 * dzv);
        const float fx0 = floorf(ix), fy0 = floorf(iy);
        const int ix0 = (int)fx0, iy0 = (int)fy0;
        const float ax = ix - fx0, ay = iy - fy0;

        // shifted-weight border handling: weights apply to (xc,xc+1),(yc,yc+1)
        float a0, a1, b0, b1;
        if (ix0 >= 0 && ix0 <= 318)      { a0 = 1.0f - ax; a1 = ax; }
        else if (ix0 == -1)              { a0 = ax;        a1 = 0.0f; }
        else if (ix0 == 319)             { a0 = 0.0f;      a1 = 1.0f - ax; }
        else                             { a0 = 0.0f;      a1 = 0.0f; }
        if (iy0 >= 0 && iy0 <= 94)       { b0 = 1.0f - ay; b1 = ay; }
        else if (iy0 == -1)              { b0 = ay;        b1 = 0.0f; }
        else if (iy0 == 95)              { b0 = 0.0f;      b1 = 1.0f - ay; }
        else                             { b0 = 0.0f;      b1 = 0.0f; }

        const int xc = min(max(ix0, 0), 318);
        const int yc = min(max(iy0, 0), 94);
        off[j] = yc * W_IN + xc;
        W00[j] = a0 * b0;  W01[j] = a1 * b0;
        W10[j] = a0 * b1;  W11[j] = a1 * b1;
        wsum += W00[j] + W01[j] + W10[j] + W11[j];
    }

    const float* Xc = X + ((size_t)b * 256 + (size_t)c0) * SLICE;
    float* oc = out + (size_t)b * 12800000 + (size_t)c0 * 50000 + item;

    if (wsum > 0.0f) {
        f32x2 g0[CG][2], g1[CG][2];
        // phase 1: 32 paired-corner dwordx2 gathers, all in flight
        #pragma unroll
        for (int cc = 0; cc < CG; ++cc) {
            const float* pc = Xc + (size_t)cc * SLICE;
            #pragma unroll
            for (int j = 0; j < 2; ++j) {
                const float* p = pc + off[j];
                g0[cc][j] = *reinterpret_cast<const f32x2u*>(p);        // row y0: x0,x0+1
                g1[cc][j] = *reinterpret_cast<const f32x2u*>(p + 320);  // row y1: x0,x0+1
            }
        }
        // phase 2: combine + plain dwordx2 stores (through L2/L3)
        #pragma unroll
        for (int cc = 0; cc < CG; ++cc) {
            f32x2 res;
            #pragma unroll
            for (int j = 0; j < 2; ++j) {
                float v = W00[j] * g0[cc][j].x;
                v = fmaf(W01[j], g0[cc][j].y, v);
                v = fmaf(W10[j], g1[cc][j].x, v);
                v = fmaf(W11[j], g1[cc][j].y, v);
                res[j] = v;
            }
            *reinterpret_cast<f32x2*>(oc + (size_t)cc * 50000) = res;
        }
    } else {
        const f32x2 z = {0.0f, 0.0f};
        #pragma unroll
        for (int cc = 0; cc < CG; ++cc) {
            *reinterpret_cast<f32x2*>(oc + (size_t)cc * 50000) = z;
        }
    }
}

extern "C" void kernel_launch(void* const* d_in, const int* in_sizes, int n_in,
                              void* d_out, int out_size, void* d_ws, size_t ws_size,
                              hipStream_t stream) {
    const float* X     = (const float*)d_in[0];   // [4,256,96,320]
    const float* calib = (const float*)d_in[1];   // [4,3,3]
    float* out = (float*)d_out;                   // [4,1280,100,100]

    dim3 grid((NP2 + 255) / 256, 128);            // 98 x (4 batches * 32 groups)
    bev_kernel<<<grid, dim3(256), 0, stream>>>(X, calib, out);
}

// Round 16
// 65.822 us; speedup vs baseline: 1.2047x; 1.2047x over previous
//
#include <hip/hip_runtime.h>

// BEVTrans: out[b, c*5+h, d, w] = bilinear_sample(X[b,c], ix(b,w,h,d), iy(b,w,h,d))
//   (calib row 2 is exactly [0,0,1] in the reference -> z = dz)
// X: [4,256,96,320] f32, calib: [4,3,3] f32, out: [4,1280,100,100] f32
//
// R15 = R13 (best, 66.1us) with CG 8->4: halves each block's L1 gather
// footprint (~100KB -> ~50KB vs 32KB L1) and doubles resident waves.
// Everything else identical: inline coords, (h,d,w) plane order, paired
// dwordx2 gathers, dwordx2 NONTEMPORAL stores (R14 proved nt is +13us:
// it keeps the write stream out of L2/L3, preserving them for X).

#define W_IN  320
#define H_IN  96
#define SLICE (H_IN * W_IN)     // 30720 floats per (b,c)
#define CG    4                 // channels per thread
#define NP2   25000             // 50000 positions / 2 per thread

typedef float f32x2 __attribute__((ext_vector_type(2)));
typedef float f32x2u __attribute__((ext_vector_type(2), aligned(4)));

__global__ __launch_bounds__(256) void bev_kernel(const float* __restrict__ X,
                                                  const float* __restrict__ calib,
                                                  float* __restrict__ out) {
    const int bcg = blockIdx.y;            // b*64 + channel_group
    const int b   = bcg >> 6;
    const int c0  = (bcg & 63) * CG;
    const int t   = blockIdx.x * 256 + threadIdx.x;   // pair index
    if (t >= NP2) return;

    const int item = t * 2;                // (h,d,w) order: out offset == item
    const int h    = item / 10000;
    const int rem  = item - h * 10000;
    const int d    = rem / 100;
    const int w0   = rem - d * 100;        // even; pair never straddles a row

    const float* cb = calib + b * 9;
    const float c00 = cb[0], c01 = cb[1], c02 = cb[2];
    const float c10 = cb[3], c11 = cb[4], c12 = cb[5];

    const float hyv = -3.0f + (float)h;
    const float dzv = 0.1f + 0.2f * (float)d;
    const float inv = 1.0f / dzv;

    int   off[2];
    float W00[2], W01[2], W10[2], W11[2];
    float wsum = 0.0f;
    #pragma unroll
    for (int j = 0; j < 2; ++j) {
        const float wxv = -9.9f + 0.2f * (float)(w0 + j);
        const float ix = 319.0f * inv * (c00 * wxv + c01 * hyv + c02 * dzv);
        const float iy =  95.0f * inv * (c10 * wxv + c11 * hyv + c12 * dzv);
        const float fx0 = floorf(ix), fy0 = floorf(iy);
        const int ix0 = (int)fx0, iy0 = (int)fy0;
        const float ax = ix - fx0, ay = iy - fy0;

        // shifted-weight border handling: weights apply to (xc,xc+1),(yc,yc+1)
        float a0, a1, b0, b1;
        if (ix0 >= 0 && ix0 <= 318)      { a0 = 1.0f - ax; a1 = ax; }
        else if (ix0 == -1)              { a0 = ax;        a1 = 0.0f; }
        else if (ix0 == 319)             { a0 = 0.0f;      a1 = 1.0f - ax; }
        else                             { a0 = 0.0f;      a1 = 0.0f; }
        if (iy0 >= 0 && iy0 <= 94)       { b0 = 1.0f - ay; b1 = ay; }
        else if (iy0 == -1)              { b0 = ay;        b1 = 0.0f; }
        else if (iy0 == 95)              { b0 = 0.0f;      b1 = 1.0f - ay; }
        else                             { b0 = 0.0f;      b1 = 0.0f; }

        const int xc = min(max(ix0, 0), 318);
        const int yc = min(max(iy0, 0), 94);
        off[j] = yc * W_IN + xc;
        W00[j] = a0 * b0;  W01[j] = a1 * b0;
        W10[j] = a0 * b1;  W11[j] = a1 * b1;
        wsum += W00[j] + W01[j] + W10[j] + W11[j];
    }

    const float* Xc = X + ((size_t)b * 256 + (size_t)c0) * SLICE;
    float* oc = out + (size_t)b * 12800000 + (size_t)c0 * 50000 + item;

    if (wsum > 0.0f) {
        f32x2 g0[CG][2], g1[CG][2];
        // phase 1: 16 paired-corner dwordx2 gathers, all in flight
        #pragma unroll
        for (int cc = 0; cc < CG; ++cc) {
            const float* pc = Xc + (size_t)cc * SLICE;
            #pragma unroll
            for (int j = 0; j < 2; ++j) {
                const float* p = pc + off[j];
                g0[cc][j] = *reinterpret_cast<const f32x2u*>(p);        // row y0: x0,x0+1
                g1[cc][j] = *reinterpret_cast<const f32x2u*>(p + 320);  // row y1: x0,x0+1
            }
        }
        // phase 2: combine + dwordx2 nt stores
        #pragma unroll
        for (int cc = 0; cc < CG; ++cc) {
            f32x2 res;
            #pragma unroll
            for (int j = 0; j < 2; ++j) {
                float v = W00[j] * g0[cc][j].x;
                v = fmaf(W01[j], g0[cc][j].y, v);
                v = fmaf(W10[j], g1[cc][j].x, v);
                v = fmaf(W11[j], g1[cc][j].y, v);
                res[j] = v;
            }
            __builtin_nontemporal_store(res, (f32x2*)(oc + (size_t)cc * 50000));
        }
    } else {
        const f32x2 z = {0.0f, 0.0f};
        #pragma unroll
        for (int cc = 0; cc < CG; ++cc) {
            __builtin_nontemporal_store(z, (f32x2*)(oc + (size_t)cc * 50000));
        }
    }
}

extern "C" void kernel_launch(void* const* d_in, const int* in_sizes, int n_in,
                              void* d_out, int out_size, void* d_ws, size_t ws_size,
                              hipStream_t stream) {
    const float* X     = (const float*)d_in[0];   // [4,256,96,320]
    const float* calib = (const float*)d_in[1];   // [4,3,3]
    float* out = (float*)d_out;                   // [4,1280,100,100]

    dim3 grid((NP2 + 255) / 256, 256);            // 98 x (4 batches * 64 groups)
    bev_kernel<<<grid, dim3(256), 0, stream>>>(X, calib, out);
}